// Round 3
// baseline (439.852 us; speedup 1.0000x reference)
//
#include <hip/hip_runtime.h>
#include <hip/hip_bf16.h>

// ---------------------------------------------------------------------------
// RelativeTransformerEncoderLayer on MI355X (gfx950).
// B=2, S=2048, D_MODEL=1024, NHEAD=16, HEAD_DIM=64, D_FF=4096.
// All device inputs/outputs fp32; internal compute bf16 MFMA + fp32 accum.
// bf16 stored as raw ushort throughout (avoids __hip_bfloat16 union issues).
// ---------------------------------------------------------------------------

#define DMODEL 1024
#define NHEAD  16
#define HD     64
#define DFF    4096
#define SEQ    2048
#define BATCH  2

using short8 = __attribute__((ext_vector_type(8))) short;
using f32x4  = __attribute__((ext_vector_type(4))) float;
typedef unsigned short bfu;   // raw bf16 bits

__device__ __forceinline__ bfu f2bf(float f) {
    unsigned int u = __float_as_uint(f);
    unsigned int r = (u + 0x7fffu + ((u >> 16) & 1u)) >> 16;   // RNE
    return (bfu)r;
}

__device__ __forceinline__ float gelu_exact(float x) {
    return 0.5f * x * (1.0f + erff(x * 0.70710678118654752f));
}

// swizzle for LDS tiles with 64-elem (128B) row stride: kills the
// stride-128B 16-way bank conflict on ds_read_b128 (guide §6 G4).
__device__ __forceinline__ int swz(int row, int colbyte) {
    return (row * 128 + colbyte) ^ ((row & 7) << 4);
}

// ---------------------------------------------------------------------------
// f32 -> bf16 bulk convert (vectorized: float4 in, 4x bf16 out)
// ---------------------------------------------------------------------------
__global__ __launch_bounds__(256) void cvt_f32_bf16(const float* __restrict__ in,
                                                    bfu* __restrict__ out, int n4) {
    int i = blockIdx.x * 256 + threadIdx.x;
    if (i >= n4) return;
    float4 v = *(const float4*)(in + (size_t)i * 4);
    uint2 o;
    o.x = (unsigned)f2bf(v.x) | ((unsigned)f2bf(v.y) << 16);
    o.y = (unsigned)f2bf(v.z) | ((unsigned)f2bf(v.w) << 16);
    *(uint2*)(out + (size_t)i * 4) = o;
}

// ---------------------------------------------------------------------------
// GEMM: C[M,N] = A[M,K] * W[N,K]^T + bias[N]  (both operands bf16, fp32 acc)
// 128x128 tile, BK=32, 4 waves, each wave 64x64 = 4x4 frags of 16x16x32 MFMA.
// MODE 0: +bias -> bf16   MODE 1: +bias -> f32   MODE 2: +bias, gelu -> bf16
// ---------------------------------------------------------------------------
template <int MODE>
__global__ __launch_bounds__(256) void gemm_bt(const bfu* __restrict__ A,
                                               const bfu* __restrict__ W,
                                               const float* __restrict__ bias,
                                               void* __restrict__ Cout,
                                               int M, int N, int K) {
    __shared__ __align__(16) bfu As[128 * 32];
    __shared__ __align__(16) bfu Bs[128 * 32];
    const int tid = threadIdx.x;
    const int wid = tid >> 6, lane = tid & 63;
    const int lg = lane >> 4, li = lane & 15;
    const int row0 = blockIdx.x * 128, col0 = blockIdx.y * 128;
    const int wr = (wid >> 1) * 64, wc = (wid & 1) * 64;
    f32x4 acc[4][4] = {};

    const int sr = tid >> 2;         // staging row 0..63 (+64 on 2nd chunk)
    const int sc = (tid & 3) * 8;    // staging col 0,8,16,24
    const bfu* Ar0 = A + (size_t)(row0 + sr) * K + sc;
    const bfu* Ar1 = A + (size_t)(row0 + 64 + sr) * K + sc;
    const bfu* Wr0 = W + (size_t)(col0 + sr) * K + sc;
    const bfu* Wr1 = W + (size_t)(col0 + 64 + sr) * K + sc;

    for (int k0 = 0; k0 < K; k0 += 32) {
        uint4 a0 = *(const uint4*)(Ar0 + k0);
        uint4 a1 = *(const uint4*)(Ar1 + k0);
        uint4 w0 = *(const uint4*)(Wr0 + k0);
        uint4 w1 = *(const uint4*)(Wr1 + k0);
        *(uint4*)(As + sr * 32 + sc) = a0;
        *(uint4*)(As + (64 + sr) * 32 + sc) = a1;
        *(uint4*)(Bs + sr * 32 + sc) = w0;
        *(uint4*)(Bs + (64 + sr) * 32 + sc) = w1;
        __syncthreads();
        short8 af[4], bf_[4];
        #pragma unroll
        for (int m = 0; m < 4; ++m)
            af[m] = *(const short8*)(As + (wr + m * 16 + li) * 32 + lg * 8);
        #pragma unroll
        for (int n = 0; n < 4; ++n)
            bf_[n] = *(const short8*)(Bs + (wc + n * 16 + li) * 32 + lg * 8);
        #pragma unroll
        for (int m = 0; m < 4; ++m)
            #pragma unroll
            for (int n = 0; n < 4; ++n)
                acc[m][n] = __builtin_amdgcn_mfma_f32_16x16x32_bf16(af[m], bf_[n], acc[m][n], 0, 0, 0);
        __syncthreads();
    }

    #pragma unroll
    for (int m = 0; m < 4; ++m) {
        #pragma unroll
        for (int n = 0; n < 4; ++n) {
            #pragma unroll
            for (int r = 0; r < 4; ++r) {
                int row = row0 + wr + m * 16 + lg * 4 + r;
                int col = col0 + wc + n * 16 + li;
                float v = acc[m][n][r] + bias[col];
                if (MODE == 2) v = gelu_exact(v);
                if (MODE == 1)
                    ((float*)Cout)[(size_t)row * N + col] = v;
                else
                    ((bfu*)Cout)[(size_t)row * N + col] = f2bf(v);
            }
        }
    }
}

// ---------------------------------------------------------------------------
// Flash-style attention with additive bias.
// Grid: (S/128, B*H). Block: 256 thr = 4 waves; wave w owns q-rows 32w..32w+31.
// KV tiles of 64. qkv layout: [B*S, 3072] bf16 (q|k|v, head h at h*64).
// scores = QK^T/8 + bias[h]; online softmax; O += P V. ctx: [B*S, 1024] bf16.
// ---------------------------------------------------------------------------
__global__ __launch_bounds__(256) void attn_kernel(const bfu* __restrict__ qkv,
                                                   const float* __restrict__ bias,
                                                   bfu* __restrict__ ctx) {
    __shared__ __align__(16) bfu Qs[128 * 64];
    __shared__ __align__(16) bfu Ks[64 * 64];
    __shared__ __align__(16) bfu Vt[64 * 64];       // transposed: [d][j]
    __shared__ __align__(16) bfu Ps[4 * 32 * 64];   // per-wave P tile
    const int tid = threadIdx.x;
    const int wid = tid >> 6, lane = tid & 63;
    const int lg = lane >> 4, li = lane & 15;
    const int q0 = blockIdx.x * 128;
    const int bh = blockIdx.y;
    const int b = bh >> 4, h = bh & 15;
    const size_t tokbase = (size_t)b * SEQ;

    // ---- stage Q tile (once) ----
    #pragma unroll
    for (int i = 0; i < 4; ++i) {
        int idx = (i * 256 + tid) * 8;
        int r = idx >> 6, c = idx & 63;
        uint4 v = *(const uint4*)(qkv + (tokbase + q0 + r) * 3072 + h * 64 + c);
        *(uint4*)((char*)Qs + swz(r, c * 2)) = v;
    }

    f32x4 o[2][4] = {};
    float mrow[2][4], lrow[2][4];
    #pragma unroll
    for (int fr = 0; fr < 2; ++fr)
        #pragma unroll
        for (int r = 0; r < 4; ++r) { mrow[fr][r] = -1e30f; lrow[fr][r] = 0.f; }

    char* pbase = (char*)Ps + wid * 32 * 128;

    for (int kt = 0; kt < SEQ; kt += 64) {
        // ---- stage K tile ----
        #pragma unroll
        for (int i = 0; i < 2; ++i) {
            int idx = (i * 256 + tid) * 8;
            int r = idx >> 6, c = idx & 63;
            uint4 v = *(const uint4*)(qkv + (tokbase + kt + r) * 3072 + 1024 + h * 64 + c);
            *(uint4*)((char*)Ks + swz(r, c * 2)) = v;
        }
        // ---- stage V transposed (coalesced global reads, b128 LDS writes) ----
        #pragma unroll
        for (int i = 0; i < 2; ++i) {
            int d = lane;            // within wave: 0..63, coalesced over d
            int jb = i * 4 + wid;    // 0..7
            bfu tmp[8];
            #pragma unroll
            for (int u = 0; u < 8; ++u)
                tmp[u] = qkv[(tokbase + kt + jb * 8 + u) * 3072 + 2048 + h * 64 + d];
            uint4 pv;
            pv.x = (unsigned)tmp[0] | ((unsigned)tmp[1] << 16);
            pv.y = (unsigned)tmp[2] | ((unsigned)tmp[3] << 16);
            pv.z = (unsigned)tmp[4] | ((unsigned)tmp[5] << 16);
            pv.w = (unsigned)tmp[6] | ((unsigned)tmp[7] << 16);
            *(uint4*)((char*)Vt + swz(d, jb * 16)) = pv;
        }
        __syncthreads();

        // ---- S = Q K^T ----
        f32x4 s[2][4] = {};
        #pragma unroll
        for (int kb = 0; kb < 2; ++kb) {
            short8 qa[2], kf[4];
            #pragma unroll
            for (int fr = 0; fr < 2; ++fr)
                qa[fr] = *(const short8*)((char*)Qs + swz(wid * 32 + fr * 16 + li, kb * 64 + lg * 16));
            #pragma unroll
            for (int nb = 0; nb < 4; ++nb)
                kf[nb] = *(const short8*)((char*)Ks + swz(nb * 16 + li, kb * 64 + lg * 16));
            #pragma unroll
            for (int fr = 0; fr < 2; ++fr)
                #pragma unroll
                for (int nb = 0; nb < 4; ++nb)
                    s[fr][nb] = __builtin_amdgcn_mfma_f32_16x16x32_bf16(qa[fr], kf[nb], s[fr][nb], 0, 0, 0);
        }

        // ---- bias + online softmax (per-row: 16-lane shuffle reduce) ----
        const float* brow = bias + (size_t)h * SEQ * SEQ;
        #pragma unroll
        for (int fr = 0; fr < 2; ++fr) {
            #pragma unroll
            for (int r = 0; r < 4; ++r) {
                int qr = q0 + wid * 32 + fr * 16 + lg * 4 + r;
                const float* bq = brow + (size_t)qr * SEQ + kt;
                float sv[4];
                float mx = -1e30f;
                #pragma unroll
                for (int nb = 0; nb < 4; ++nb) {
                    float v = s[fr][nb][r] * 0.125f + bq[nb * 16 + li];
                    sv[nb] = v;
                    mx = fmaxf(mx, v);
                }
                #pragma unroll
                for (int off = 8; off; off >>= 1) mx = fmaxf(mx, __shfl_xor(mx, off));
                float mnew = fmaxf(mrow[fr][r], mx);
                float sf = __expf(mrow[fr][r] - mnew);
                mrow[fr][r] = mnew;
                float rs = 0.f;
                #pragma unroll
                for (int nb = 0; nb < 4; ++nb) {
                    float p = __expf(sv[nb] - mnew);
                    rs += p;
                    s[fr][nb][r] = p;
                }
                #pragma unroll
                for (int off = 8; off; off >>= 1) rs += __shfl_xor(rs, off);
                lrow[fr][r] = lrow[fr][r] * sf + rs;
                #pragma unroll
                for (int dc = 0; dc < 4; ++dc) o[fr][dc][r] *= sf;
            }
        }

        // ---- P (C-layout) -> LDS -> re-read as A fragments ----
        #pragma unroll
        for (int fr = 0; fr < 2; ++fr)
            #pragma unroll
            for (int nb = 0; nb < 4; ++nb)
                #pragma unroll
                for (int r = 0; r < 4; ++r) {
                    int prow = fr * 16 + lg * 4 + r;
                    *(bfu*)(pbase + swz(prow, (nb * 16 + li) * 2)) = f2bf(s[fr][nb][r]);
                }

        // ---- O += P V ----
        #pragma unroll
        for (int jb = 0; jb < 2; ++jb) {
            short8 pa[2], vb[4];
            #pragma unroll
            for (int fr = 0; fr < 2; ++fr)
                pa[fr] = *(const short8*)(pbase + swz(fr * 16 + li, jb * 64 + lg * 16));
            #pragma unroll
            for (int dc = 0; dc < 4; ++dc)
                vb[dc] = *(const short8*)((char*)Vt + swz(dc * 16 + li, jb * 64 + lg * 16));
            #pragma unroll
            for (int fr = 0; fr < 2; ++fr)
                #pragma unroll
                for (int dc = 0; dc < 4; ++dc)
                    o[fr][dc] = __builtin_amdgcn_mfma_f32_16x16x32_bf16(pa[fr], vb[dc], o[fr][dc], 0, 0, 0);
        }
        __syncthreads();
    }

    // ---- normalize + write ctx ----
    #pragma unroll
    for (int fr = 0; fr < 2; ++fr)
        #pragma unroll
        for (int dc = 0; dc < 4; ++dc)
            #pragma unroll
            for (int r = 0; r < 4; ++r) {
                int qr = q0 + wid * 32 + fr * 16 + lg * 4 + r;
                int d = dc * 16 + li;
                float v = o[fr][dc][r] / lrow[fr][r];
                ctx[(tokbase + qr) * 1024 + h * 64 + d] = f2bf(v);
            }
}

// ---------------------------------------------------------------------------
// x = LayerNorm(a + b) * g + be.  One block per row (D=1024), 256 thr x 4 f32.
// Writes fp32 (xf) and optionally bf16 (xb) copies.
// ---------------------------------------------------------------------------
__global__ __launch_bounds__(256) void residual_ln_kernel(const float* __restrict__ a,
                                                          const float* __restrict__ b,
                                                          const float* __restrict__ g,
                                                          const float* __restrict__ be,
                                                          float* __restrict__ xf,
                                                          bfu* __restrict__ xb) {
    const int row = blockIdx.x, t = threadIdx.x;
    const size_t off = (size_t)row * DMODEL + t * 4;
    float4 av = *(const float4*)(a + off);
    float4 bv = *(const float4*)(b + off);
    float4 v;
    v.x = av.x + bv.x; v.y = av.y + bv.y; v.z = av.z + bv.z; v.w = av.w + bv.w;
    float s  = v.x + v.y + v.z + v.w;
    float sq = v.x * v.x + v.y * v.y + v.z * v.z + v.w * v.w;
    #pragma unroll
    for (int o2 = 32; o2; o2 >>= 1) { s += __shfl_xor(s, o2); sq += __shfl_xor(sq, o2); }
    __shared__ float red[8];
    const int wid = t >> 6, lane = t & 63;
    if (lane == 0) { red[wid] = s; red[4 + wid] = sq; }
    __syncthreads();
    s  = red[0] + red[1] + red[2] + red[3];
    sq = red[4] + red[5] + red[6] + red[7];
    float mu  = s * (1.0f / DMODEL);
    float var = sq * (1.0f / DMODEL) - mu * mu;
    float rstd = rsqrtf(var + 1e-5f);
    float4 gv  = *(const float4*)(g + t * 4);
    float4 bev = *(const float4*)(be + t * 4);
    float4 ov;
    ov.x = (v.x - mu) * rstd * gv.x + bev.x;
    ov.y = (v.y - mu) * rstd * gv.y + bev.y;
    ov.z = (v.z - mu) * rstd * gv.z + bev.z;
    ov.w = (v.w - mu) * rstd * gv.w + bev.w;
    *(float4*)(xf + off) = ov;
    if (xb) {
        uint2 o;
        o.x = (unsigned)f2bf(ov.x) | ((unsigned)f2bf(ov.y) << 16);
        o.y = (unsigned)f2bf(ov.z) | ((unsigned)f2bf(ov.w) << 16);
        *(uint2*)(xb + off) = o;
    }
}

// ---------------------------------------------------------------------------
extern "C" void kernel_launch(void* const* d_in, const int* in_sizes, int n_in,
                              void* d_out, int out_size, void* d_ws, size_t ws_size,
                              hipStream_t stream) {
    const float* src    = (const float*)d_in[0];
    const float* abias  = (const float*)d_in[1];
    const float* qkv_w  = (const float*)d_in[2];
    const float* qkv_b  = (const float*)d_in[3];
    const float* out_w  = (const float*)d_in[4];
    const float* out_b  = (const float*)d_in[5];
    const float* lin1_w = (const float*)d_in[6];
    const float* lin1_b = (const float*)d_in[7];
    const float* lin2_w = (const float*)d_in[8];
    const float* lin2_b = (const float*)d_in[9];
    const float* ln1_g  = (const float*)d_in[10];
    const float* ln1_b  = (const float*)d_in[11];
    const float* ln2_g  = (const float*)d_in[12];
    const float* ln2_b  = (const float*)d_in[13];
    float* out = (float*)d_out;

    const int T = BATCH * SEQ;                    // 4096 tokens
    char* w = (char*)d_ws;
    auto take = [&](size_t bytes) { char* p = w; w += (bytes + 255) & ~(size_t)255; return p; };
    bfu*   src_bf  = (bfu*)take((size_t)T * DMODEL * 2);
    bfu*   qkvw_bf = (bfu*)take((size_t)3 * DMODEL * DMODEL * 2);
    bfu*   outw_bf = (bfu*)take((size_t)DMODEL * DMODEL * 2);
    bfu*   l1w_bf  = (bfu*)take((size_t)DFF * DMODEL * 2);
    bfu*   l2w_bf  = (bfu*)take((size_t)DMODEL * DFF * 2);
    bfu*   qkv_bf  = (bfu*)take((size_t)T * 3 * DMODEL * 2);
    bfu*   ctx_bf  = (bfu*)take((size_t)T * DMODEL * 2);
    float* attn_o  = (float*)take((size_t)T * DMODEL * 4);
    float* x_f     = (float*)take((size_t)T * DMODEL * 4);
    bfu*   x_bf    = (bfu*)take((size_t)T * DMODEL * 2);
    bfu*   h1_bf   = (bfu*)take((size_t)T * DFF * 2);
    float* ff_f    = (float*)take((size_t)T * DMODEL * 4);

    auto cvt = [&](const float* in, bfu* o_, size_t n) {
        int n4 = (int)(n / 4);
        cvt_f32_bf16<<<(n4 + 255) / 256, 256, 0, stream>>>(in, o_, n4);
    };
    cvt(src,    src_bf,  (size_t)T * DMODEL);
    cvt(qkv_w,  qkvw_bf, (size_t)3 * DMODEL * DMODEL);
    cvt(out_w,  outw_bf, (size_t)DMODEL * DMODEL);
    cvt(lin1_w, l1w_bf,  (size_t)DFF * DMODEL);
    cvt(lin2_w, l2w_bf,  (size_t)DMODEL * DFF);

    // qkv = src @ qkv_w^T + qkv_b            [4096, 3072] bf16
    gemm_bt<0><<<dim3(T / 128, (3 * DMODEL) / 128), 256, 0, stream>>>(
        src_bf, qkvw_bf, qkv_b, qkv_bf, T, 3 * DMODEL, DMODEL);
    // attention -> ctx                        [4096, 1024] bf16
    attn_kernel<<<dim3(SEQ / 128, BATCH * NHEAD), 256, 0, stream>>>(qkv_bf, abias, ctx_bf);
    // attn_out = ctx @ out_w^T + out_b        [4096, 1024] f32
    gemm_bt<1><<<dim3(T / 128, DMODEL / 128), 256, 0, stream>>>(
        ctx_bf, outw_bf, out_b, attn_o, T, DMODEL, DMODEL);
    // x = LN(src + attn_out)                  f32 + bf16
    residual_ln_kernel<<<T, 256, 0, stream>>>(src, attn_o, ln1_g, ln1_b, x_f, x_bf);
    // h1 = gelu(x @ lin1_w^T + lin1_b)        [4096, 4096] bf16
    gemm_bt<2><<<dim3(T / 128, DFF / 128), 256, 0, stream>>>(
        x_bf, l1w_bf, lin1_b, h1_bf, T, DFF, DMODEL);
    // ff = h1 @ lin2_w^T + lin2_b             [4096, 1024] f32
    gemm_bt<1><<<dim3(T / 128, DMODEL / 128), 256, 0, stream>>>(
        h1_bf, l2w_bf, lin2_b, ff_f, T, DMODEL, DFF);
    // out = LN(x + ff)                        f32 -> d_out
    residual_ln_kernel<<<T, 256, 0, stream>>>(x_f, ff_f, ln2_g, ln2_b, out, nullptr);
}

// Round 4
// 417.074 us; speedup vs baseline: 1.0546x; 1.0546x over previous
//
#include <hip/hip_runtime.h>
#include <hip/hip_bf16.h>

// ---------------------------------------------------------------------------
// RelativeTransformerEncoderLayer on MI355X (gfx950).
// B=2, S=2048, D_MODEL=1024, NHEAD=16, HEAD_DIM=64, D_FF=4096.
// fp32 in/out; internal bf16 MFMA + fp32 accum.
// R4: GEMM = m97 structure (global_load_lds 16B, BK=32, linear LDS);
//     attn = 64-row Q blocks, reg-prefetched bias, setprio on MFMA.
// ---------------------------------------------------------------------------

#define DMODEL 1024
#define NHEAD  16
#define HD     64
#define DFF    4096
#define SEQ    2048
#define BATCH  2

using short8 = __attribute__((ext_vector_type(8))) short;
using f32x4  = __attribute__((ext_vector_type(4))) float;
typedef unsigned short bfu;   // raw bf16 bits

__device__ __forceinline__ bfu f2bf(float f) {
    unsigned int u = __float_as_uint(f);
    unsigned int r = (u + 0x7fffu + ((u >> 16) & 1u)) >> 16;   // RNE
    return (bfu)r;
}

__device__ __forceinline__ float gelu_exact(float x) {
    return 0.5f * x * (1.0f + erff(x * 0.70710678118654752f));
}

// async 16B global -> LDS (lds dest = wave-uniform base + lane*16)
__device__ __forceinline__ void gload16(const void* g, void* l) {
    __builtin_amdgcn_global_load_lds(
        (const __attribute__((address_space(1))) void*)g,
        (__attribute__((address_space(3))) void*)l, 16, 0, 0);
}

// swizzle for LDS tiles with 64-elem (128B) row stride (attn tiles only)
__device__ __forceinline__ int swz(int row, int colbyte) {
    return (row * 128 + colbyte) ^ ((row & 7) << 4);
}

// ---------------------------------------------------------------------------
// f32 -> bf16 bulk convert
// ---------------------------------------------------------------------------
__global__ __launch_bounds__(256) void cvt_f32_bf16(const float* __restrict__ in,
                                                    bfu* __restrict__ out, int n4) {
    int i = blockIdx.x * 256 + threadIdx.x;
    if (i >= n4) return;
    float4 v = *(const float4*)(in + (size_t)i * 4);
    uint2 o;
    o.x = (unsigned)f2bf(v.x) | ((unsigned)f2bf(v.y) << 16);
    o.y = (unsigned)f2bf(v.z) | ((unsigned)f2bf(v.w) << 16);
    *(uint2*)(out + (size_t)i * 4) = o;
}

// ---------------------------------------------------------------------------
// GEMM: C[M,N] = A[M,K] * W[N,K]^T + bias[N]   (m97 structure)
// 128x128 tile, BK=32, 4 waves (2x2 of 64x64), global_load_lds 16B staging.
// MODE 0: +bias -> bf16   MODE 1: +bias -> f32   MODE 2: +bias, gelu -> bf16
// ---------------------------------------------------------------------------
template <int MODE>
__global__ __launch_bounds__(256) void gemm_bt(const bfu* __restrict__ A,
                                               const bfu* __restrict__ W,
                                               const float* __restrict__ bias,
                                               void* __restrict__ Cout,
                                               int M, int N, int K) {
    __shared__ __align__(16) bfu As[128 * 32];
    __shared__ __align__(16) bfu Bs[128 * 32];
    const int tid = threadIdx.x;
    const int wid = tid >> 6, lane = tid & 63;
    const int lg = lane >> 4, li = lane & 15;
    const int row0 = blockIdx.x * 128, col0 = blockIdx.y * 128;
    const int wr = (wid >> 1) * 64, wc = (wid & 1) * 64;
    f32x4 acc[4][4] = {};

    // staging geometry: 128x32 bf16 tile = 8KB = 512 x 16B chunks.
    // chunk = j*256 + tid; row = chunk>>2; colb = (chunk&3)*16 bytes.
    const int ch_row0 = (tid >> 2);          // chunk row for j=0 (0..63)
    const int ch_colb = (tid & 3) * 16;      // byte col within row
    const bfu* Ag0 = A + (size_t)(row0 + ch_row0) * K + (ch_colb >> 1);
    const bfu* Ag1 = A + (size_t)(row0 + 64 + ch_row0) * K + (ch_colb >> 1);
    const bfu* Wg0 = W + (size_t)(col0 + ch_row0) * K + (ch_colb >> 1);
    const bfu* Wg1 = W + (size_t)(col0 + 64 + ch_row0) * K + (ch_colb >> 1);
    char* Al0 = (char*)As + wid * 1024;
    char* Al1 = (char*)As + 4096 + wid * 1024;
    char* Bl0 = (char*)Bs + wid * 1024;
    char* Bl1 = (char*)Bs + 4096 + wid * 1024;

    for (int k0 = 0; k0 < K; k0 += 32) {
        gload16(Ag0 + k0, Al0);
        gload16(Ag1 + k0, Al1);
        gload16(Wg0 + k0, Bl0);
        gload16(Wg1 + k0, Bl1);
        __syncthreads();               // drains vmcnt -> tiles resident
        short8 af[4], bf_[4];
        #pragma unroll
        for (int m = 0; m < 4; ++m)
            af[m] = *(const short8*)(As + (wr + m * 16 + li) * 32 + lg * 8);
        #pragma unroll
        for (int n = 0; n < 4; ++n)
            bf_[n] = *(const short8*)(Bs + (wc + n * 16 + li) * 32 + lg * 8);
        #pragma unroll
        for (int m = 0; m < 4; ++m)
            #pragma unroll
            for (int n = 0; n < 4; ++n)
                acc[m][n] = __builtin_amdgcn_mfma_f32_16x16x32_bf16(af[m], bf_[n], acc[m][n], 0, 0, 0);
        __syncthreads();               // readers done before next stage
    }

    #pragma unroll
    for (int m = 0; m < 4; ++m) {
        #pragma unroll
        for (int n = 0; n < 4; ++n) {
            #pragma unroll
            for (int r = 0; r < 4; ++r) {
                int row = row0 + wr + m * 16 + lg * 4 + r;
                int col = col0 + wc + n * 16 + li;
                float v = acc[m][n][r] + bias[col];
                if (MODE == 2) v = gelu_exact(v);
                if (MODE == 1)
                    ((float*)Cout)[(size_t)row * N + col] = v;
                else
                    ((bfu*)Cout)[(size_t)row * N + col] = f2bf(v);
            }
        }
    }
}

// ---------------------------------------------------------------------------
// Flash-style attention with additive bias.
// Grid: (S/64, B*H) = (32, 32). Block: 256 thr = 4 waves; wave w owns q-rows
// 16w..16w+15. KV tiles of 64. Bias prefetched into regs before each barrier.
// ---------------------------------------------------------------------------
__global__ __launch_bounds__(256) void attn_kernel(const bfu* __restrict__ qkv,
                                                   const float* __restrict__ bias,
                                                   bfu* __restrict__ ctx) {
    __shared__ __align__(16) bfu Qs[64 * 64];
    __shared__ __align__(16) bfu Ks[64 * 64];
    __shared__ __align__(16) bfu Vt[64 * 64];       // transposed: [d][j]
    __shared__ __align__(16) bfu Ps[4 * 16 * 64];   // per-wave P tile
    const int tid = threadIdx.x;
    const int wid = tid >> 6, lane = tid & 63;
    const int lg = lane >> 4, li = lane & 15;
    const int q0 = blockIdx.x * 64;
    const int bh = blockIdx.y;
    const int b = bh >> 4, h = bh & 15;
    const size_t tokbase = (size_t)b * SEQ;

    // ---- stage Q tile (once) ----
    #pragma unroll
    for (int i = 0; i < 2; ++i) {
        int idx = (i * 256 + tid) * 8;
        int r = idx >> 6, c = idx & 63;
        uint4 v = *(const uint4*)(qkv + (tokbase + q0 + r) * 3072 + h * 64 + c);
        *(uint4*)((char*)Qs + swz(r, c * 2)) = v;
    }

    f32x4 o[4] = {};
    float mrow[4], lrow[4];
    #pragma unroll
    for (int r = 0; r < 4; ++r) { mrow[r] = -1e30f; lrow[r] = 0.f; }

    char* pbase = (char*)Ps + wid * 2048;           // 16*64*2B per wave
    const float* brow = bias + (size_t)h * SEQ * SEQ;
    const int qrbase = q0 + wid * 16 + lg * 4;

    for (int kt = 0; kt < SEQ; kt += 64) {
        // ---- stage K tile ----
        #pragma unroll
        for (int i = 0; i < 2; ++i) {
            int idx = (i * 256 + tid) * 8;
            int r = idx >> 6, c = idx & 63;
            uint4 v = *(const uint4*)(qkv + (tokbase + kt + r) * 3072 + 1024 + h * 64 + c);
            *(uint4*)((char*)Ks + swz(r, c * 2)) = v;
        }
        // ---- stage V transposed ----
        #pragma unroll
        for (int i = 0; i < 2; ++i) {
            int d = lane;
            int jb = i * 4 + wid;
            bfu tmp[8];
            #pragma unroll
            for (int u = 0; u < 8; ++u)
                tmp[u] = qkv[(tokbase + kt + jb * 8 + u) * 3072 + 2048 + h * 64 + d];
            uint4 pv;
            pv.x = (unsigned)tmp[0] | ((unsigned)tmp[1] << 16);
            pv.y = (unsigned)tmp[2] | ((unsigned)tmp[3] << 16);
            pv.z = (unsigned)tmp[4] | ((unsigned)tmp[5] << 16);
            pv.w = (unsigned)tmp[6] | ((unsigned)tmp[7] << 16);
            *(uint4*)((char*)Vt + swz(d, jb * 16)) = pv;
        }
        // ---- prefetch bias for this tile into regs (hides under MFMA) ----
        float breg[4][4];
        #pragma unroll
        for (int r = 0; r < 4; ++r)
            #pragma unroll
            for (int nb = 0; nb < 4; ++nb)
                breg[r][nb] = brow[(size_t)(qrbase + r) * SEQ + kt + nb * 16 + li];
        __syncthreads();

        // ---- S = Q K^T ----
        f32x4 s[4] = {};
        __builtin_amdgcn_s_setprio(1);
        #pragma unroll
        for (int cb = 0; cb < 2; ++cb) {
            short8 qa = *(const short8*)((char*)Qs + swz(wid * 16 + li, cb * 64 + lg * 16));
            short8 kf[4];
            #pragma unroll
            for (int nb = 0; nb < 4; ++nb)
                kf[nb] = *(const short8*)((char*)Ks + swz(nb * 16 + li, cb * 64 + lg * 16));
            #pragma unroll
            for (int nb = 0; nb < 4; ++nb)
                s[nb] = __builtin_amdgcn_mfma_f32_16x16x32_bf16(qa, kf[nb], s[nb], 0, 0, 0);
        }
        __builtin_amdgcn_s_setprio(0);

        // ---- bias + online softmax (reduce across 16 li lanes) ----
        #pragma unroll
        for (int r = 0; r < 4; ++r) {
            float sv[4];
            float mx = -1e30f;
            #pragma unroll
            for (int nb = 0; nb < 4; ++nb) {
                float v = s[nb][r] * 0.125f + breg[r][nb];
                sv[nb] = v;
                mx = fmaxf(mx, v);
            }
            #pragma unroll
            for (int off = 8; off; off >>= 1) mx = fmaxf(mx, __shfl_xor(mx, off));
            float mnew = fmaxf(mrow[r], mx);
            float sf = __expf(mrow[r] - mnew);
            mrow[r] = mnew;
            float rs = 0.f;
            #pragma unroll
            for (int nb = 0; nb < 4; ++nb) {
                float p = __expf(sv[nb] - mnew);
                rs += p;
                s[nb][r] = p;
            }
            #pragma unroll
            for (int off = 8; off; off >>= 1) rs += __shfl_xor(rs, off);
            lrow[r] = lrow[r] * sf + rs;
            #pragma unroll
            for (int dc = 0; dc < 4; ++dc) o[dc][r] *= sf;
        }

        // ---- P (C-layout) -> per-wave LDS -> A fragments ----
        #pragma unroll
        for (int nb = 0; nb < 4; ++nb)
            #pragma unroll
            for (int r = 0; r < 4; ++r)
                *(bfu*)(pbase + swz(lg * 4 + r, (nb * 16 + li) * 2)) = f2bf(s[nb][r]);

        // ---- O += P V ----
        __builtin_amdgcn_s_setprio(1);
        #pragma unroll
        for (int jb = 0; jb < 2; ++jb) {
            short8 pa = *(const short8*)(pbase + swz(li, jb * 64 + lg * 16));
            short8 vb[4];
            #pragma unroll
            for (int dc = 0; dc < 4; ++dc)
                vb[dc] = *(const short8*)((char*)Vt + swz(dc * 16 + li, jb * 64 + lg * 16));
            #pragma unroll
            for (int dc = 0; dc < 4; ++dc)
                o[dc] = __builtin_amdgcn_mfma_f32_16x16x32_bf16(pa, vb[dc], o[dc], 0, 0, 0);
        }
        __builtin_amdgcn_s_setprio(0);
        __syncthreads();
    }

    // ---- normalize + write ctx ----
    #pragma unroll
    for (int dc = 0; dc < 4; ++dc)
        #pragma unroll
        for (int r = 0; r < 4; ++r) {
            int qr = qrbase + r;
            int d = dc * 16 + li;
            float v = o[dc][r] / lrow[r];
            ctx[(tokbase + qr) * 1024 + h * 64 + d] = f2bf(v);
        }
}

// ---------------------------------------------------------------------------
// x = LayerNorm(a + b) * g + be.  One block per row (D=1024).
// ---------------------------------------------------------------------------
__global__ __launch_bounds__(256) void residual_ln_kernel(const float* __restrict__ a,
                                                          const float* __restrict__ b,
                                                          const float* __restrict__ g,
                                                          const float* __restrict__ be,
                                                          float* __restrict__ xf,
                                                          bfu* __restrict__ xb) {
    const int row = blockIdx.x, t = threadIdx.x;
    const size_t off = (size_t)row * DMODEL + t * 4;
    float4 av = *(const float4*)(a + off);
    float4 bv = *(const float4*)(b + off);
    float4 v;
    v.x = av.x + bv.x; v.y = av.y + bv.y; v.z = av.z + bv.z; v.w = av.w + bv.w;
    float s  = v.x + v.y + v.z + v.w;
    float sq = v.x * v.x + v.y * v.y + v.z * v.z + v.w * v.w;
    #pragma unroll
    for (int o2 = 32; o2; o2 >>= 1) { s += __shfl_xor(s, o2); sq += __shfl_xor(sq, o2); }
    __shared__ float red[8];
    const int wid = t >> 6, lane = t & 63;
    if (lane == 0) { red[wid] = s; red[4 + wid] = sq; }
    __syncthreads();
    s  = red[0] + red[1] + red[2] + red[3];
    sq = red[4] + red[5] + red[6] + red[7];
    float mu  = s * (1.0f / DMODEL);
    float var = sq * (1.0f / DMODEL) - mu * mu;
    float rstd = rsqrtf(var + 1e-5f);
    float4 gv  = *(const float4*)(g + t * 4);
    float4 bev = *(const float4*)(be + t * 4);
    float4 ov;
    ov.x = (v.x - mu) * rstd * gv.x + bev.x;
    ov.y = (v.y - mu) * rstd * gv.y + bev.y;
    ov.z = (v.z - mu) * rstd * gv.z + bev.z;
    ov.w = (v.w - mu) * rstd * gv.w + bev.w;
    *(float4*)(xf + off) = ov;
    if (xb) {
        uint2 o;
        o.x = (unsigned)f2bf(ov.x) | ((unsigned)f2bf(ov.y) << 16);
        o.y = (unsigned)f2bf(ov.z) | ((unsigned)f2bf(ov.w) << 16);
        *(uint2*)(xb + off) = o;
    }
}

// ---------------------------------------------------------------------------
extern "C" void kernel_launch(void* const* d_in, const int* in_sizes, int n_in,
                              void* d_out, int out_size, void* d_ws, size_t ws_size,
                              hipStream_t stream) {
    const float* src    = (const float*)d_in[0];
    const float* abias  = (const float*)d_in[1];
    const float* qkv_w  = (const float*)d_in[2];
    const float* qkv_b  = (const float*)d_in[3];
    const float* out_w  = (const float*)d_in[4];
    const float* out_b  = (const float*)d_in[5];
    const float* lin1_w = (const float*)d_in[6];
    const float* lin1_b = (const float*)d_in[7];
    const float* lin2_w = (const float*)d_in[8];
    const float* lin2_b = (const float*)d_in[9];
    const float* ln1_g  = (const float*)d_in[10];
    const float* ln1_b  = (const float*)d_in[11];
    const float* ln2_g  = (const float*)d_in[12];
    const float* ln2_b  = (const float*)d_in[13];
    float* out = (float*)d_out;

    const int T = BATCH * SEQ;                    // 4096 tokens
    char* w = (char*)d_ws;
    auto take = [&](size_t bytes) { char* p = w; w += (bytes + 255) & ~(size_t)255; return p; };
    bfu*   src_bf  = (bfu*)take((size_t)T * DMODEL * 2);
    bfu*   qkvw_bf = (bfu*)take((size_t)3 * DMODEL * DMODEL * 2);
    bfu*   outw_bf = (bfu*)take((size_t)DMODEL * DMODEL * 2);
    bfu*   l1w_bf  = (bfu*)take((size_t)DFF * DMODEL * 2);
    bfu*   l2w_bf  = (bfu*)take((size_t)DMODEL * DFF * 2);
    bfu*   qkv_bf  = (bfu*)take((size_t)T * 3 * DMODEL * 2);
    bfu*   ctx_bf  = (bfu*)take((size_t)T * DMODEL * 2);
    float* attn_o  = (float*)take((size_t)T * DMODEL * 4);
    float* x_f     = (float*)take((size_t)T * DMODEL * 4);
    bfu*   x_bf    = (bfu*)take((size_t)T * DMODEL * 2);
    bfu*   h1_bf   = (bfu*)take((size_t)T * DFF * 2);
    float* ff_f    = (float*)take((size_t)T * DMODEL * 4);

    auto cvt = [&](const float* in, bfu* o_, size_t n) {
        int n4 = (int)(n / 4);
        cvt_f32_bf16<<<(n4 + 255) / 256, 256, 0, stream>>>(in, o_, n4);
    };
    cvt(src,    src_bf,  (size_t)T * DMODEL);
    cvt(qkv_w,  qkvw_bf, (size_t)3 * DMODEL * DMODEL);
    cvt(out_w,  outw_bf, (size_t)DMODEL * DMODEL);
    cvt(lin1_w, l1w_bf,  (size_t)DFF * DMODEL);
    cvt(lin2_w, l2w_bf,  (size_t)DMODEL * DFF);

    // qkv = src @ qkv_w^T + qkv_b            [4096, 3072] bf16
    gemm_bt<0><<<dim3(T / 128, (3 * DMODEL) / 128), 256, 0, stream>>>(
        src_bf, qkvw_bf, qkv_b, qkv_bf, T, 3 * DMODEL, DMODEL);
    // attention -> ctx                        [4096, 1024] bf16
    attn_kernel<<<dim3(SEQ / 64, BATCH * NHEAD), 256, 0, stream>>>(qkv_bf, abias, ctx_bf);
    // attn_out = ctx @ out_w^T + out_b        [4096, 1024] f32
    gemm_bt<1><<<dim3(T / 128, DMODEL / 128), 256, 0, stream>>>(
        ctx_bf, outw_bf, out_b, attn_o, T, DMODEL, DMODEL);
    // x = LN(src + attn_out)                  f32 + bf16
    residual_ln_kernel<<<T, 256, 0, stream>>>(src, attn_o, ln1_g, ln1_b, x_f, x_bf);
    // h1 = gelu(x @ lin1_w^T + lin1_b)        [4096, 4096] bf16
    gemm_bt<2><<<dim3(T / 128, DFF / 128), 256, 0, stream>>>(
        x_bf, l1w_bf, lin1_b, h1_bf, T, DFF, DMODEL);
    // ff = h1 @ lin2_w^T + lin2_b             [4096, 1024] f32
    gemm_bt<1><<<dim3(T / 128, DMODEL / 128), 256, 0, stream>>>(
        h1_bf, l2w_bf, lin2_b, ff_f, T, DMODEL, DFF);
    // out = LN(x + ff)                        f32 -> d_out
    residual_ln_kernel<<<T, 256, 0, stream>>>(x_f, ff_f, ln2_g, ln2_b, out, nullptr);
}